// Round 6
// baseline (376.223 us; speedup 1.0000x reference)
//
#include <hip/hip_runtime.h>

// Problem constants (B=4, S=4096, D=2048, E=8, K=2, cap_factor=1.25)
#define TOKENS      16384
#define DIM         2048
#define D4          512          // DIM / 4 (float4 units)
#define NE          8            // experts
#define CAPACITY    5120         // int(16384*2/8*1.25)
#define NASSIGN     (TOKENS * 2) // 32768 top-k assignments

#define NTHREADS    512          // 8 waves/block
#define NBLOCKS     512          // 2 blocks/CU; 4096 waves x 2 pair-iters x 2 tokens

// d_out layout (all float32, tuple order):
//   [0, 32768)        expert_indices as float  [B,S,K]
//   [32768, 65536)    expert_weights           [B,S,K]
//   [65536]           load_balance_loss
//   [65537, 98305)    expert_mask              [B,S,K]

__device__ __forceinline__ float dot4(const float4 a, const float4 b) {
    return a.x * b.x + a.y * b.y + a.z * b.z + a.w * b.w;
}

// VGPR discipline is the whole game (r1/r5 post-mortems: >128 live regs ->
// scratch spill -> 100+ MB of HBM round-trips). Exactly ONE token pair is in
// flight per wave: 64 x-VGPRs + 16 acc + w pipeline + addresses ~ 110 regs.
// Latency is hidden by 4 waves/SIMD (16 waves/CU), not by deeper ILP.
__global__ __launch_bounds__(NTHREADS, 4) void router_main(
    const float* __restrict__ x, const float* __restrict__ wg,
    float* __restrict__ out_idx, float* __restrict__ out_w,
    float* __restrict__ imp_g, int* __restrict__ cnt_g)
{
    __shared__ float4 wlds[NE * D4];     // 64 KiB -> 2 blocks/CU
    __shared__ float  imp_lds[NE];
    __shared__ int    cnt_lds[NE];

    const int tid  = threadIdx.x;
    const int lane = tid & 63;
    const int wave = tid >> 6;
    const int q    = blockIdx.x * (NTHREADS / 64) + wave;  // 0..4095
    const int tok0 = q * 4;   // this wave's 4 tokens (32 KB contiguous)

    if (tid < NE) { imp_lds[tid] = 0.f; cnt_lds[tid] = 0; }

    // Stage w (64 KiB) into LDS: 8 coalesced float4 per thread.
    const float4* wg4 = (const float4*)wg;
#pragma unroll
    for (int k = 0; k < (NE * D4) / NTHREADS; k++)
        wlds[tid + k * NTHREADS] = wg4[tid + k * NTHREADS];
    __syncthreads();

    const float4* x4 = (const float4*)x;

    for (int pp = 0; pp < 2; pp++) {
        const int t0 = tok0 + 2 * pp;
        const float4* xb = x4 + (size_t)t0 * D4 + lane;

        // 16 independent dwordx4 loads (8 KB/token pair), single latency wall.
        float4 xr0[8], xr1[8];
#pragma unroll
        for (int c = 0; c < 8; c++) xr0[c] = xb[c * 64];
#pragma unroll
        for (int c = 0; c < 8; c++) xr1[c] = xb[D4 + c * 64];

        float acc0[NE], acc1[NE];
#pragma unroll
        for (int e = 0; e < NE; e++) { acc0[e] = 0.f; acc1[e] = 0.f; }

        // Each w ds_read_b128 feeds both tokens (w reuse x2: DS pipe ~10 us
        // per CU vs HBM 21 us -> DS off the critical path).
#pragma unroll
        for (int c = 0; c < 8; c++) {
#pragma unroll
            for (int e = 0; e < NE; e++) {
                const float4 w = wlds[e * D4 + c * 64 + lane];
                acc0[e] += dot4(xr0[c], w);
                acc1[e] += dot4(xr1[c], w);
            }
        }

        // fold (xor 1): even lanes keep token0, odd token1; then butterfly.
        const int p1 = lane & 1;
        float v[NE];
#pragma unroll
        for (int e = 0; e < NE; e++) {
            float snd = p1 ? acc0[e] : acc1[e];
            float kp  = p1 ? acc1[e] : acc0[e];
            v[e] = kp + __shfl_xor(snd, 1, 64);
        }
#pragma unroll
        for (int off = 2; off <= 32; off <<= 1) {
#pragma unroll
            for (int e = 0; e < NE; e++) v[e] += __shfl_xor(v[e], off, 64);
        }
        // lane 0 holds full logits of token t0, lane 1 of t0+1

        if (lane < 2) {
            const int t = t0 + lane;

            // softmax over 8 (importance accumulation)
            float m = v[0];
#pragma unroll
            for (int e = 1; e < NE; e++) m = fmaxf(m, v[e]);
            float pe[NE], s = 0.f;
#pragma unroll
            for (int e = 0; e < NE; e++) { pe[e] = expf(v[e] - m); s += pe[e]; }
            const float inv = 1.f / s;
#pragma unroll
            for (int e = 0; e < NE; e++) atomicAdd(&imp_lds[e], pe[e] * inv);

            // top-2 (ties -> lowest index, jax top_k semantics)
            int i1 = 0; float v1 = v[0];
#pragma unroll
            for (int e = 1; e < NE; e++) { if (v[e] > v1) { v1 = v[e]; i1 = e; } }
            int i2 = -1; float v2 = -3.4e38f;
#pragma unroll
            for (int e = 0; e < NE; e++) { if (e != i1 && v[e] > v2) { v2 = v[e]; i2 = e; } }

            const float w1 = 1.f / (1.f + expf(v2 - v1));   // renorm pair
            atomicAdd(&cnt_lds[i1], 1);
            atomicAdd(&cnt_lds[i2], 1);

            out_idx[2 * t]     = (float)i1;
            out_idx[2 * t + 1] = (float)i2;
            out_w[2 * t]       = w1;
            out_w[2 * t + 1]   = 1.f - w1;
        }
    }

    __syncthreads();
    if (tid < NE)          atomicAdd(&imp_g[tid], imp_lds[tid]);
    else if (tid < 2 * NE) atomicAdd(&cnt_g[tid - NE], cnt_lds[tid - NE]);
}

// Capacity mask (exact rank rule, matches lexsort((-wf, idxf)) + rank<capacity)
// plus the load-balance loss scalar.
__global__ void mask_loss_kernel(
    const float* __restrict__ out_idx, const float* __restrict__ out_w,
    float* __restrict__ mask, float* __restrict__ loss_out,
    const float* __restrict__ imp_g, const int* __restrict__ cnt_g)
{
    const int i = blockIdx.x * blockDim.x + threadIdx.x;
    if (i < NASSIGN) {
        const int e = (int)out_idx[i];
        const int c = cnt_g[e];
        float mk = 1.f;
        if (c > CAPACITY) {   // statistically never taken; exact fallback
            const float wi = out_w[i];
            int rank = 0;
            for (int j = 0; j < NASSIGN; j++) {
                if ((int)out_idx[j] == e) {
                    const float wj = out_w[j];
                    if (wj > wi || (wj == wi && j < i)) rank++;
                }
            }
            mk = (rank < CAPACITY) ? 1.f : 0.f;
        }
        mask[i] = mk;
    }
    if (blockIdx.x == 0 && threadIdx.x == 0) {
        float si = 0.f, sc = 0.f, dot = 0.f;
#pragma unroll
        for (int e = 0; e < NE; e++) {
            const float im = imp_g[e];
            const float ct = (float)cnt_g[e];
            si += im; sc += ct; dot += im * ct;
        }
        loss_out[0] = (float)NE * dot / (si * sc);
    }
}

extern "C" void kernel_launch(void* const* d_in, const int* in_sizes, int n_in,
                              void* d_out, int out_size, void* d_ws, size_t ws_size,
                              hipStream_t stream)
{
    const float* x  = (const float*)d_in[0];   // [4,4096,2048] f32
    const float* wg = (const float*)d_in[1];   // [8,2048] f32

    float* out      = (float*)d_out;
    float* out_idx  = out;            // 32768
    float* out_w    = out + 32768;    // 32768
    float* loss     = out + 65536;    // 1
    float* mask     = out + 65537;    // 32768

    float* imp_g = (float*)d_ws;                     // 8 f32
    int*   cnt_g = (int*)((char*)d_ws + 64);         // 8 i32

    hipMemsetAsync(d_ws, 0, 128, stream);

    router_main<<<NBLOCKS, NTHREADS, 0, stream>>>(x, wg, out_idx, out_w, imp_g, cnt_g);
    mask_loss_kernel<<<(NASSIGN + NTHREADS - 1) / NTHREADS, NTHREADS, 0, stream>>>(
        out_idx, out_w, mask, loss, imp_g, cnt_g);
}

// Round 7
// 198.723 us; speedup vs baseline: 1.8932x; 1.8932x over previous
//
#include <hip/hip_runtime.h>

// Problem constants (B=4, S=4096, D=2048, E=8, K=2, cap_factor=1.25)
#define TOKENS      16384
#define DIM         2048
#define D4          512          // DIM / 4 (float4 units)
#define NE          8            // experts
#define CAPACITY    5120         // int(16384*2/8*1.25)
#define NASSIGN     (TOKENS * 2) // 32768 top-k assignments

#define NTHREADS    512          // 8 waves/block
#define NBLOCKS     512          // 2 blocks/CU; each wave: 2 pairs = 4 tokens

// d_out layout (all float32, tuple order):
//   [0, 32768)        expert_indices as float  [B,S,K]
//   [32768, 65536)    expert_weights           [B,S,K]
//   [65536]           load_balance_loss
//   [65537, 98305)    expert_mask              [B,S,K]

__device__ __forceinline__ float dot4(const float4 a, const float4 b) {
    return a.x * b.x + a.y * b.y + a.z * b.z + a.w * b.w;
}

// Register-budget-first design (r1/r5/r6 post-mortems: every spill costs
// 100-300 MB of HBM round-trips). The chunk loop ROLLS (#pragma unroll 1)
// with a 1-deep x prefetch, so only 4 float4 of x are ever live (~16 regs);
// steady-state live set ~80 regs vs the 128 default budget. NO second
// __launch_bounds__ arg: hipcc treats it as CUDA min-blocks/CU (r6: arg=4
// forced VGPR=64 and 314 MB of spill writes).
__global__ __launch_bounds__(NTHREADS) void router_main(
    const float* __restrict__ x, const float* __restrict__ wg,
    float* __restrict__ out_idx, float* __restrict__ out_w,
    float* __restrict__ imp_g, int* __restrict__ cnt_g)
{
    __shared__ float4 wlds[NE * D4];     // 64 KiB -> 2 blocks/CU, 16 waves/CU
    __shared__ float  imp_lds[NE];
    __shared__ int    cnt_lds[NE];

    const int tid  = threadIdx.x;
    const int lane = tid & 63;
    const int wave = tid >> 6;
    const int q    = blockIdx.x * (NTHREADS / 64) + wave;  // 0..4095
    const int tok0 = q * 4;   // this wave's 4 tokens (32 KB contiguous)

    if (tid < NE) { imp_lds[tid] = 0.f; cnt_lds[tid] = 0; }

    // Stage w (64 KiB) into LDS: 8 coalesced float4 per thread.
    const float4* wg4 = (const float4*)wg;
#pragma unroll
    for (int k = 0; k < (NE * D4) / NTHREADS; k++)
        wlds[tid + k * NTHREADS] = wg4[tid + k * NTHREADS];
    __syncthreads();

    const float4* x4 = (const float4*)x;

#pragma unroll 1
    for (int pp = 0; pp < 2; pp++) {
        const int t0 = tok0 + 2 * pp;
        const float4* xp0 = x4 + (size_t)t0 * D4 + lane;   // token t0
        const float4* xp1 = xp0 + D4;                      // token t0+1

        float acc0[NE], acc1[NE];
#pragma unroll
        for (int e = 0; e < NE; e++) { acc0[e] = 0.f; acc1[e] = 0.f; }

        // chunk 0 preload (2 float4)
        float4 a0 = xp0[0];
        float4 b0 = xp1[0];

#pragma unroll 1
        for (int cc = 0; cc < 4; cc++) {
            const int c0 = 2 * cc, c1 = 2 * cc + 1;

            // prefetch odd chunk while computing even chunk
            float4 a1 = xp0[c1 * 64];
            float4 b1 = xp1[c1 * 64];
#pragma unroll
            for (int e = 0; e < NE; e++) {
                const float4 w = wlds[e * D4 + c0 * 64 + lane];
                acc0[e] += dot4(a0, w);
                acc1[e] += dot4(b0, w);
            }

            // prefetch next even chunk (guarded: chunk 8 doesn't exist)
            if (cc < 3) {
                a0 = xp0[(c0 + 2) * 64];
                b0 = xp1[(c0 + 2) * 64];
            }
#pragma unroll
            for (int e = 0; e < NE; e++) {
                const float4 w = wlds[e * D4 + c1 * 64 + lane];
                acc0[e] += dot4(a1, w);
                acc1[e] += dot4(b1, w);
            }
        }

        // fold (xor 1): even lanes keep token0, odd token1; then butterfly.
        const int p1 = lane & 1;
        float v[NE];
#pragma unroll
        for (int e = 0; e < NE; e++) {
            float snd = p1 ? acc0[e] : acc1[e];
            float kp  = p1 ? acc1[e] : acc0[e];
            v[e] = kp + __shfl_xor(snd, 1, 64);
        }
#pragma unroll
        for (int off = 2; off <= 32; off <<= 1) {
#pragma unroll
            for (int e = 0; e < NE; e++) v[e] += __shfl_xor(v[e], off, 64);
        }
        // lane 0 holds full logits of token t0, lane 1 of t0+1

        if (lane < 2) {
            const int t = t0 + lane;

            // softmax over 8 (importance accumulation)
            float m = v[0];
#pragma unroll
            for (int e = 1; e < NE; e++) m = fmaxf(m, v[e]);
            float pe[NE], s = 0.f;
#pragma unroll
            for (int e = 0; e < NE; e++) { pe[e] = expf(v[e] - m); s += pe[e]; }
            const float inv = 1.f / s;
#pragma unroll
            for (int e = 0; e < NE; e++) atomicAdd(&imp_lds[e], pe[e] * inv);

            // top-2 (ties -> lowest index, jax top_k semantics)
            int i1 = 0; float v1 = v[0];
#pragma unroll
            for (int e = 1; e < NE; e++) { if (v[e] > v1) { v1 = v[e]; i1 = e; } }
            int i2 = -1; float v2 = -3.4e38f;
#pragma unroll
            for (int e = 0; e < NE; e++) { if (e != i1 && v[e] > v2) { v2 = v[e]; i2 = e; } }

            const float w1 = 1.f / (1.f + expf(v2 - v1));   // renorm pair
            atomicAdd(&cnt_lds[i1], 1);
            atomicAdd(&cnt_lds[i2], 1);

            out_idx[2 * t]     = (float)i1;
            out_idx[2 * t + 1] = (float)i2;
            out_w[2 * t]       = w1;
            out_w[2 * t + 1]   = 1.f - w1;
        }
    }

    __syncthreads();
    if (tid < NE)          atomicAdd(&imp_g[tid], imp_lds[tid]);
    else if (tid < 2 * NE) atomicAdd(&cnt_g[tid - NE], cnt_lds[tid - NE]);
}

// Capacity mask (exact rank rule, matches lexsort((-wf, idxf)) + rank<capacity)
// plus the load-balance loss scalar.
__global__ void mask_loss_kernel(
    const float* __restrict__ out_idx, const float* __restrict__ out_w,
    float* __restrict__ mask, float* __restrict__ loss_out,
    const float* __restrict__ imp_g, const int* __restrict__ cnt_g)
{
    const int i = blockIdx.x * blockDim.x + threadIdx.x;
    if (i < NASSIGN) {
        const int e = (int)out_idx[i];
        const int c = cnt_g[e];
        float mk = 1.f;
        if (c > CAPACITY) {   // statistically never taken; exact fallback
            const float wi = out_w[i];
            int rank = 0;
            for (int j = 0; j < NASSIGN; j++) {
                if ((int)out_idx[j] == e) {
                    const float wj = out_w[j];
                    if (wj > wi || (wj == wi && j < i)) rank++;
                }
            }
            mk = (rank < CAPACITY) ? 1.f : 0.f;
        }
        mask[i] = mk;
    }
    if (blockIdx.x == 0 && threadIdx.x == 0) {
        float si = 0.f, sc = 0.f, dot = 0.f;
#pragma unroll
        for (int e = 0; e < NE; e++) {
            const float im = imp_g[e];
            const float ct = (float)cnt_g[e];
            si += im; sc += ct; dot += im * ct;
        }
        loss_out[0] = (float)NE * dot / (si * sc);
    }
}

extern "C" void kernel_launch(void* const* d_in, const int* in_sizes, int n_in,
                              void* d_out, int out_size, void* d_ws, size_t ws_size,
                              hipStream_t stream)
{
    const float* x  = (const float*)d_in[0];   // [4,4096,2048] f32
    const float* wg = (const float*)d_in[1];   // [8,2048] f32

    float* out      = (float*)d_out;
    float* out_idx  = out;            // 32768
    float* out_w    = out + 32768;    // 32768
    float* loss     = out + 65536;    // 1
    float* mask     = out + 65537;    // 32768

    float* imp_g = (float*)d_ws;                     // 8 f32
    int*   cnt_g = (int*)((char*)d_ws + 64);         // 8 i32

    hipMemsetAsync(d_ws, 0, 128, stream);

    router_main<<<NBLOCKS, NTHREADS, 0, stream>>>(x, wg, out_idx, out_w, imp_g, cnt_g);
    mask_loss_kernel<<<(NASSIGN + NTHREADS - 1) / NTHREADS, NTHREADS, 0, stream>>>(
        out_idx, out_w, mask, loss, imp_g, cnt_g);
}